// Round 4
// baseline (258.624 us; speedup 1.0000x reference)
//
#include <hip/hip_runtime.h>
#include <cfloat>

typedef __bf16 bf16x8 __attribute__((ext_vector_type(8)));
typedef float f32x16 __attribute__((ext_vector_type(16)));

namespace {
constexpr int kHW = 4096;     // 64*64 spatial per image
constexpr int kC = 64;        // channels == code dim
constexpr float kInvN = 1.0f / 65536.0f;

// ws layout (bytes): [0, 294912): A-frags (32 chunks * 9 slots * 64 lanes * 16B)
//                    [294912, +4096): hist (1024 u32)   [+4096, +4): lossacc
// Frag slot order per chunk: 0..3 = Ah(ks), 4..7 = Al(ks), 8 = bias.

// ---------------- prep: build -2*C bf16-split fragments + bias frag ---------
// 32 blocks x 256 thr; wave wv builds k-slot ks=wv (hi+lo frags).
__global__ __launch_bounds__(256) void prep_kernel(
    const float* __restrict__ cb, uint4* __restrict__ frags,
    unsigned int* __restrict__ hist, float* __restrict__ lossacc) {
  const int c = blockIdx.x;        // chunk of 32 codes
  const int t = threadIdx.x;
  const int lane = t & 63, wv = t >> 6;
  const int lo = lane & 31, hi = lane >> 5;
  const int code = c * 32 + lo;
  const int ks = wv;

  const float* row = cb + code * kC + ks * 16 + hi * 8;
  float4 v0 = *reinterpret_cast<const float4*>(row);
  float4 v1 = *reinterpret_cast<const float4*>(row + 4);
  float vv[8] = {v0.x, v0.y, v0.z, v0.w, v1.x, v1.y, v1.z, v1.w};
  bf16x8 fh, fl;
  #pragma unroll
  for (int e = 0; e < 8; ++e) {
    float v = -2.0f * vv[e];
    __bf16 h = (__bf16)v;
    fh[e] = h;
    fl[e] = (__bf16)(v - (float)h);
  }
  frags[(c * 9 + ks) * 64 + lane] = *reinterpret_cast<uint4*>(&fh);
  frags[(c * 9 + 4 + ks) * 64 + lane] = *reinterpret_cast<uint4*>(&fl);

  if (wv == 0) {
    bf16x8 fb;
    #pragma unroll
    for (int e = 0; e < 8; ++e) fb[e] = (__bf16)0.0f;
    if (hi == 0) {
      float s = 0.0f;
      #pragma unroll
      for (int d = 0; d < kC; d += 4) {
        float4 v = *reinterpret_cast<const float4*>(cb + code * kC + d);
        s = fmaf(v.x, v.x, fmaf(v.y, v.y, fmaf(v.z, v.z, fmaf(v.w, v.w, s))));
      }
      __bf16 h = (__bf16)s;
      fb[0] = h;
      fb[1] = (__bf16)(s - (float)h);
    }
    frags[(c * 9 + 8) * 64 + lane] = *reinterpret_cast<uint4*>(&fb);
  }
  if (t < 32) hist[c * 32 + t] = 0u;
  if (c == 0 && t == 0) lossacc[0] = 0.0f;
}

// ---------------- fused: MFMA argmin + output + loss ------------------------
// Block = 4 waves owning 64 sites. Wave wv: site-group (wv&1), K-half (wv>>1)
// of 16 chunks. Cross-half argmin merge via LDS; fused output epilogue.
__global__ __launch_bounds__(256, 4) void vq_kernel(
    const float* __restrict__ in, const bf16x8* __restrict__ frags,
    const float* __restrict__ cb, unsigned int* __restrict__ hist,
    float* __restrict__ lossacc, float* __restrict__ qout) {
  __shared__ float sVal[4][32];
  __shared__ int sIdxW[4][32];
  __shared__ int sIdx[64];
  const int t = threadIdx.x;
  const int lane = t & 63, wv = t >> 6;
  const int lo = lane & 31, hi = lane >> 5;
  const int sg2 = wv & 1, kh = wv >> 1;
  const int site = blockIdx.x * 64 + sg2 * 32 + lo;
  const int b = site >> 12, hw = site & 4095;
  const float* xp = in + b * (kC * kHW) + hw;

  // --- X fragments: bf16 hi/lo split, 8 consecutive d per lane-half ---
  bf16x8 Bh[4], Bl[4];
  #pragma unroll
  for (int ks = 0; ks < 4; ++ks) {
    #pragma unroll
    for (int e = 0; e < 8; ++e) {
      const int d = ks * 16 + hi * 8 + e;
      float v = xp[d * kHW];
      __bf16 h = (__bf16)v;
      Bh[ks][e] = h;
      Bl[ks][e] = (__bf16)(v - (float)h);
    }
  }
  bf16x8 ones;
  #pragma unroll
  for (int e = 0; e < 8; ++e) ones[e] = (__bf16)0.0f;
  if (hi == 0) { ones[0] = (__bf16)1.0f; ones[1] = (__bf16)1.0f; }
  f32x16 zero;
  #pragma unroll
  for (int r = 0; r < 16; ++r) zero[r] = 0.0f;

  float best[16];
  int bch[16];
  #pragma unroll
  for (int r = 0; r < 16; ++r) { best[r] = FLT_MAX; bch[r] = 0; }

  const bf16x8* fA = frags + lane;   // entry j of chunk c at fA[(c*9+j)*64]

  bf16x8 A0[9], A1[9];
  auto prefetch = [&](bf16x8(&F)[9], int c) {
    #pragma unroll
    for (int j = 0; j < 9; ++j) F[j] = fA[(c * 9 + j) * 64];
  };
  auto compute = [&](const bf16x8(&F)[9], int c) {
    // dist = bias + (-2c).x via 3-pass bf16 split; single chained accumulator
    f32x16 a = __builtin_amdgcn_mfma_f32_32x32x16_bf16(F[8], ones, zero, 0, 0, 0);
    #pragma unroll
    for (int ks = 0; ks < 4; ++ks)
      a = __builtin_amdgcn_mfma_f32_32x32x16_bf16(F[ks], Bh[ks], a, 0, 0, 0);
    #pragma unroll
    for (int ks = 0; ks < 4; ++ks)
      a = __builtin_amdgcn_mfma_f32_32x32x16_bf16(F[4 + ks], Bh[ks], a, 0, 0, 0);
    #pragma unroll
    for (int ks = 0; ks < 4; ++ks)
      a = __builtin_amdgcn_mfma_f32_32x32x16_bf16(F[ks], Bl[ks], a, 0, 0, 0);
    #pragma unroll
    for (int r = 0; r < 16; ++r) {
      bool p = a[r] < best[r];         // strict < : earliest chunk wins ties
      best[r] = p ? a[r] : best[r];
      bch[r] = p ? c : bch[r];
    }
  };

  const int c0 = kh * 16;
  prefetch(A0, c0);
  #pragma unroll 1
  for (int c = c0; c < c0 + 16; c += 2) {
    prefetch(A1, c + 1);
    compute(A0, c);
    if (c + 2 < c0 + 16) prefetch(A0, c + 2);
    compute(A1, c + 1);
  }

  // --- per-lane (val, idx) reduce over 16 acc rows, then half-merge ---
  float bv = best[0];
  int bidx = bch[0] * 32 + (hi << 2);       // kloc(r=0) = 0 + 4*hi
  #pragma unroll
  for (int r = 1; r < 16; ++r) {
    const int kloc = (r & 3) + 8 * (r >> 2) + (hi << 2);
    int idx = bch[r] * 32 + kloc;
    float v = best[r];
    if (v < bv || (v == bv && idx < bidx)) { bv = v; bidx = idx; }
  }
  float ov = __shfl_xor(bv, 32, 64);
  int oi = __shfl_xor(bidx, 32, 64);
  if (ov < bv || (ov == bv && oi < bidx)) { bv = ov; bidx = oi; }
  if (hi == 0) {
    sVal[wv][lo] = bv;
    sIdxW[wv][lo] = bidx;
  }
  __syncthreads();
  // waves 0,1 (K-half 0) merge with partner wave (wv+2, K-half 1)
  if (wv < 2 && hi == 0) {
    float v2 = sVal[wv + 2][lo];
    int i2 = sIdxW[wv + 2][lo];
    if (v2 < bv || (v2 == bv && i2 < bidx)) { bv = v2; bidx = i2; }
    sIdx[sg2 * 32 + lo] = bidx;
    atomicAdd(&hist[bidx], 1u);
  }
  __syncthreads();

  // --- output: quantized = x + (q - x), fused loss ---
  {
    const int s2 = t & 63;
    const int dbase = (t >> 6) * 16;
    const int gsite = blockIdx.x * 64 + s2;
    const int b2 = gsite >> 12, hw2 = gsite & 4095;
    const int code = sIdx[s2];
    const float* xr = in + b2 * (kC * kHW) + hw2;
    const float* qr = cb + code * kC + dbase;
    float* op = qout + b2 * (kC * kHW) + hw2;
    float ls = 0.0f;
    #pragma unroll
    for (int j = 0; j < 16; j += 4) {
      float4 qv = *reinterpret_cast<const float4*>(qr + j);
      float q[4] = {qv.x, qv.y, qv.z, qv.w};
      #pragma unroll
      for (int u = 0; u < 4; ++u) {
        const int d = dbase + j + u;
        float xv = xr[d * kHW];
        float diff = q[u] - xv;              // q - x
        ls = fmaf(diff, diff, ls);
        op[d * kHW] = xv + diff;             // straight-through: x + (q-x)
      }
    }
    #pragma unroll
    for (int off = 32; off; off >>= 1) ls += __shfl_xor(ls, off, 64);
    if (lane == 0) atomicAdd(lossacc, ls);
  }
}

// ---------------- finalize: loss scalar + perplexity ------------------------
__global__ __launch_bounds__(1024) void finalize_kernel(
    const unsigned int* __restrict__ hist, const float* __restrict__ lossacc,
    const float* __restrict__ beta, float* __restrict__ out) {
  __shared__ float red[16];
  const int t = threadIdx.x;
  float e = (float)hist[t] * kInvN;
  float term = e * logf(e + 1e-10f);
  #pragma unroll
  for (int off = 32; off; off >>= 1) term += __shfl_xor(term, off, 64);
  if ((t & 63) == 0) red[t >> 6] = term;
  __syncthreads();
  if (t == 0) {
    float h = 0.0f;
    #pragma unroll
    for (int i = 0; i < 16; ++i) h += red[i];
    out[1 + 4194304] = expf(-h);                                  // perplexity
    out[0] = lossacc[0] * (1.0f + beta[0]) * 10.0f / 4194304.0f;  // loss
  }
}
}  // namespace

extern "C" void kernel_launch(void* const* d_in, const int* in_sizes, int n_in,
                              void* d_out, int out_size, void* d_ws, size_t ws_size,
                              hipStream_t stream) {
  const float* inputs = (const float*)d_in[0];   // [16,64,64,64] fp32
  const float* cb = (const float*)d_in[1];       // [1024,64] fp32
  const float* beta = (const float*)d_in[2];     // scalar
  float* out = (float*)d_out;                    // [1 + 4194304 + 1]

  uint4* frags = (uint4*)d_ws;                                        // 294912 B
  unsigned int* hist = (unsigned int*)((char*)d_ws + 294912);         // 4 KB
  float* lossacc = (float*)((char*)d_ws + 294912 + 4096);             // 4 B

  prep_kernel<<<32, 256, 0, stream>>>(cb, (uint4*)frags, hist, lossacc);
  vq_kernel<<<1024, 256, 0, stream>>>(inputs, (const bf16x8*)d_ws, cb, hist,
                                      lossacc, out + 1);
  finalize_kernel<<<1, 1024, 0, stream>>>(hist, lossacc, beta, out);
}

// Round 5
// 139.120 us; speedup vs baseline: 1.8590x; 1.8590x over previous
//
#include <hip/hip_runtime.h>
#include <cfloat>

typedef __bf16 bf16x8 __attribute__((ext_vector_type(8)));
typedef float f32x16 __attribute__((ext_vector_type(16)));

namespace {
constexpr int kHW = 4096;     // 64*64 spatial per image
constexpr int kC = 64;        // channels == code dim
constexpr float kInvN = 1.0f / 65536.0f;

// ws layout (bytes): [0, 294912): A-frags (32 chunks * 9 slots * 64 lanes * 16B)
//                    [294912, +4096): hist (1024 u32)   [+4096, +4): lossacc
// Frag slot order per chunk: 0..3 = Ah(ks), 4..7 = Al(ks), 8 = bias.

// ---------------- prep: build -2*C bf16-split fragments + bias frag ---------
// 32 blocks x 256 thr; wave wv builds k-slot ks=wv (hi+lo frags).
__global__ __launch_bounds__(256) void prep_kernel(
    const float* __restrict__ cb, uint4* __restrict__ frags,
    unsigned int* __restrict__ hist, float* __restrict__ lossacc) {
  const int c = blockIdx.x;        // chunk of 32 codes
  const int t = threadIdx.x;
  const int lane = t & 63, wv = t >> 6;
  const int lo = lane & 31, hi = lane >> 5;
  const int code = c * 32 + lo;
  const int ks = wv;

  const float* row = cb + code * kC + ks * 16 + hi * 8;
  float4 v0 = *reinterpret_cast<const float4*>(row);
  float4 v1 = *reinterpret_cast<const float4*>(row + 4);
  float vv[8] = {v0.x, v0.y, v0.z, v0.w, v1.x, v1.y, v1.z, v1.w};
  bf16x8 fh, fl;
  #pragma unroll
  for (int e = 0; e < 8; ++e) {
    float v = -2.0f * vv[e];
    __bf16 h = (__bf16)v;
    fh[e] = h;
    fl[e] = (__bf16)(v - (float)h);
  }
  frags[(c * 9 + ks) * 64 + lane] = *reinterpret_cast<uint4*>(&fh);
  frags[(c * 9 + 4 + ks) * 64 + lane] = *reinterpret_cast<uint4*>(&fl);

  if (wv == 0) {
    bf16x8 fb;
    #pragma unroll
    for (int e = 0; e < 8; ++e) fb[e] = (__bf16)0.0f;
    if (hi == 0) {
      float s = 0.0f;
      #pragma unroll
      for (int d = 0; d < kC; d += 4) {
        float4 v = *reinterpret_cast<const float4*>(cb + code * kC + d);
        s = fmaf(v.x, v.x, fmaf(v.y, v.y, fmaf(v.z, v.z, fmaf(v.w, v.w, s))));
      }
      __bf16 h = (__bf16)s;
      fb[0] = h;
      fb[1] = (__bf16)(s - (float)h);
    }
    frags[(c * 9 + 8) * 64 + lane] = *reinterpret_cast<uint4*>(&fb);
  }
  if (t < 32) hist[c * 32 + t] = 0u;
  if (c == 0 && t == 0) lossacc[0] = 0.0f;
}

// ---------------- fused: MFMA argmin + output + loss ------------------------
// Block = 4 waves owning 64 sites. Wave wv: site-group (wv&1), K-half (wv>>1)
// of 16 chunks. Cross-half argmin merge via LDS; fused output epilogue.
// NOTE: no min-waves clause — forcing 4 waves/EU (R4) capped VGPR at 64 and
// spilled the 72-reg prefetch state to scratch (hbm_bytes 25x, 3x slowdown).
__global__ __launch_bounds__(256) void vq_kernel(
    const float* __restrict__ in, const bf16x8* __restrict__ frags,
    const float* __restrict__ cb, unsigned int* __restrict__ hist,
    float* __restrict__ lossacc, float* __restrict__ qout) {
  __shared__ float sVal[4][32];
  __shared__ int sIdxW[4][32];
  __shared__ int sIdx[64];
  const int t = threadIdx.x;
  const int lane = t & 63, wv = t >> 6;
  const int lo = lane & 31, hi = lane >> 5;
  const int sg2 = wv & 1, kh = wv >> 1;
  const int site = blockIdx.x * 64 + sg2 * 32 + lo;
  const int b = site >> 12, hw = site & 4095;
  const float* xp = in + b * (kC * kHW) + hw;

  // --- X fragments: bf16 hi/lo split, 8 consecutive d per lane-half ---
  bf16x8 Bh[4], Bl[4];
  #pragma unroll
  for (int ks = 0; ks < 4; ++ks) {
    #pragma unroll
    for (int e = 0; e < 8; ++e) {
      const int d = ks * 16 + hi * 8 + e;
      float v = xp[d * kHW];
      __bf16 h = (__bf16)v;
      Bh[ks][e] = h;
      Bl[ks][e] = (__bf16)(v - (float)h);
    }
  }
  bf16x8 ones;
  #pragma unroll
  for (int e = 0; e < 8; ++e) ones[e] = (__bf16)0.0f;
  if (hi == 0) { ones[0] = (__bf16)1.0f; ones[1] = (__bf16)1.0f; }
  f32x16 zero;
  #pragma unroll
  for (int r = 0; r < 16; ++r) zero[r] = 0.0f;

  float best[16];
  int bch[16];
  #pragma unroll
  for (int r = 0; r < 16; ++r) { best[r] = FLT_MAX; bch[r] = 0; }

  const bf16x8* fA = frags + lane;   // entry j of chunk c at fA[(c*9+j)*64]

  bf16x8 A0[9], A1[9];
  auto prefetch = [&](bf16x8(&F)[9], int c) {
    #pragma unroll
    for (int j = 0; j < 9; ++j) F[j] = fA[(c * 9 + j) * 64];
  };
  auto compute = [&](const bf16x8(&F)[9], int c) {
    // dist = bias + (-2c).x via 3-pass bf16 split; single chained accumulator
    f32x16 a = __builtin_amdgcn_mfma_f32_32x32x16_bf16(F[8], ones, zero, 0, 0, 0);
    #pragma unroll
    for (int ks = 0; ks < 4; ++ks)
      a = __builtin_amdgcn_mfma_f32_32x32x16_bf16(F[ks], Bh[ks], a, 0, 0, 0);
    #pragma unroll
    for (int ks = 0; ks < 4; ++ks)
      a = __builtin_amdgcn_mfma_f32_32x32x16_bf16(F[4 + ks], Bh[ks], a, 0, 0, 0);
    #pragma unroll
    for (int ks = 0; ks < 4; ++ks)
      a = __builtin_amdgcn_mfma_f32_32x32x16_bf16(F[ks], Bl[ks], a, 0, 0, 0);
    #pragma unroll
    for (int r = 0; r < 16; ++r) {
      bool p = a[r] < best[r];         // strict < : earliest chunk wins ties
      best[r] = p ? a[r] : best[r];
      bch[r] = p ? c : bch[r];
    }
  };

  const int c0 = kh * 16;
  prefetch(A0, c0);
  #pragma unroll 1
  for (int c = c0; c < c0 + 16; c += 2) {
    prefetch(A1, c + 1);
    compute(A0, c);
    if (c + 2 < c0 + 16) prefetch(A0, c + 2);
    compute(A1, c + 1);
  }

  // --- per-lane (val, idx) reduce over 16 acc rows, then half-merge ---
  float bv = best[0];
  int bidx = bch[0] * 32 + (hi << 2);       // kloc(r=0) = 0 + 4*hi
  #pragma unroll
  for (int r = 1; r < 16; ++r) {
    const int kloc = (r & 3) + 8 * (r >> 2) + (hi << 2);
    int idx = bch[r] * 32 + kloc;
    float v = best[r];
    if (v < bv || (v == bv && idx < bidx)) { bv = v; bidx = idx; }
  }
  float ov = __shfl_xor(bv, 32, 64);
  int oi = __shfl_xor(bidx, 32, 64);
  if (ov < bv || (ov == bv && oi < bidx)) { bv = ov; bidx = oi; }
  if (hi == 0) {
    sVal[wv][lo] = bv;
    sIdxW[wv][lo] = bidx;
  }
  __syncthreads();
  // waves 0,1 (K-half 0) merge with partner wave (wv+2, K-half 1)
  if (wv < 2 && hi == 0) {
    float v2 = sVal[wv + 2][lo];
    int i2 = sIdxW[wv + 2][lo];
    if (v2 < bv || (v2 == bv && i2 < bidx)) { bv = v2; bidx = i2; }
    sIdx[sg2 * 32 + lo] = bidx;
    atomicAdd(&hist[bidx], 1u);
  }
  __syncthreads();

  // --- output: quantized = x + (q - x), fused loss ---
  {
    const int s2 = t & 63;
    const int dbase = (t >> 6) * 16;
    const int gsite = blockIdx.x * 64 + s2;
    const int b2 = gsite >> 12, hw2 = gsite & 4095;
    const int code = sIdx[s2];
    const float* xr = in + b2 * (kC * kHW) + hw2;
    const float* qr = cb + code * kC + dbase;
    float* op = qout + b2 * (kC * kHW) + hw2;
    float ls = 0.0f;
    #pragma unroll
    for (int j = 0; j < 16; j += 4) {
      float4 qv = *reinterpret_cast<const float4*>(qr + j);
      float q[4] = {qv.x, qv.y, qv.z, qv.w};
      #pragma unroll
      for (int u = 0; u < 4; ++u) {
        const int d = dbase + j + u;
        float xv = xr[d * kHW];
        float diff = q[u] - xv;              // q - x
        ls = fmaf(diff, diff, ls);
        op[d * kHW] = xv + diff;             // straight-through: x + (q-x)
      }
    }
    #pragma unroll
    for (int off = 32; off; off >>= 1) ls += __shfl_xor(ls, off, 64);
    if (lane == 0) atomicAdd(lossacc, ls);
  }
}

// ---------------- finalize: loss scalar + perplexity ------------------------
__global__ __launch_bounds__(1024) void finalize_kernel(
    const unsigned int* __restrict__ hist, const float* __restrict__ lossacc,
    const float* __restrict__ beta, float* __restrict__ out) {
  __shared__ float red[16];
  const int t = threadIdx.x;
  float e = (float)hist[t] * kInvN;
  float term = e * logf(e + 1e-10f);
  #pragma unroll
  for (int off = 32; off; off >>= 1) term += __shfl_xor(term, off, 64);
  if ((t & 63) == 0) red[t >> 6] = term;
  __syncthreads();
  if (t == 0) {
    float h = 0.0f;
    #pragma unroll
    for (int i = 0; i < 16; ++i) h += red[i];
    out[1 + 4194304] = expf(-h);                                  // perplexity
    out[0] = lossacc[0] * (1.0f + beta[0]) * 10.0f / 4194304.0f;  // loss
  }
}
}  // namespace

extern "C" void kernel_launch(void* const* d_in, const int* in_sizes, int n_in,
                              void* d_out, int out_size, void* d_ws, size_t ws_size,
                              hipStream_t stream) {
  const float* inputs = (const float*)d_in[0];   // [16,64,64,64] fp32
  const float* cb = (const float*)d_in[1];       // [1024,64] fp32
  const float* beta = (const float*)d_in[2];     // scalar
  float* out = (float*)d_out;                    // [1 + 4194304 + 1]

  uint4* frags = (uint4*)d_ws;                                        // 294912 B
  unsigned int* hist = (unsigned int*)((char*)d_ws + 294912);         // 4 KB
  float* lossacc = (float*)((char*)d_ws + 294912 + 4096);             // 4 B

  prep_kernel<<<32, 256, 0, stream>>>(cb, (uint4*)frags, hist, lossacc);
  vq_kernel<<<1024, 256, 0, stream>>>(inputs, (const bf16x8*)d_ws, cb, hist,
                                      lossacc, out + 1);
  finalize_kernel<<<1, 1024, 0, stream>>>(hist, lossacc, beta, out);
}

// Round 7
// 138.347 us; speedup vs baseline: 1.8694x; 1.0056x over previous
//
#include <hip/hip_runtime.h>
#include <cfloat>

typedef __bf16 bf16x8 __attribute__((ext_vector_type(8)));
typedef float f32x16 __attribute__((ext_vector_type(16)));

namespace {
constexpr int kHW = 4096;     // 64*64 spatial per image
constexpr int kC = 64;        // channels == code dim
constexpr float kInvN = 1.0f / 65536.0f;
constexpr int kChunkBytes = 9216;   // 9 frags * 64 lanes * 16B

// ws layout (bytes): [0, 294912): A-frags (32 chunks * 9 slots * 64 lanes * 16B)
//                    [294912, +4096): hist (1024 u32)   [+4096, +4): lossacc
// Frag slot order per chunk: 0..3 = Ah(ks), 4..7 = Al(ks), 8 = bias.

// ---------------- prep: build -2*C bf16-split fragments + bias frag ---------
__global__ __launch_bounds__(256) void prep_kernel(
    const float* __restrict__ cb, uint4* __restrict__ frags,
    unsigned int* __restrict__ hist, float* __restrict__ lossacc) {
  const int c = blockIdx.x;        // chunk of 32 codes
  const int t = threadIdx.x;
  const int lane = t & 63, wv = t >> 6;
  const int lo = lane & 31, hi = lane >> 5;
  const int code = c * 32 + lo;
  const int ks = wv;

  const float* row = cb + code * kC + ks * 16 + hi * 8;
  float4 v0 = *reinterpret_cast<const float4*>(row);
  float4 v1 = *reinterpret_cast<const float4*>(row + 4);
  float vv[8] = {v0.x, v0.y, v0.z, v0.w, v1.x, v1.y, v1.z, v1.w};
  bf16x8 fh, fl;
  #pragma unroll
  for (int e = 0; e < 8; ++e) {
    float v = -2.0f * vv[e];
    __bf16 h = (__bf16)v;
    fh[e] = h;
    fl[e] = (__bf16)(v - (float)h);
  }
  frags[(c * 9 + ks) * 64 + lane] = *reinterpret_cast<uint4*>(&fh);
  frags[(c * 9 + 4 + ks) * 64 + lane] = *reinterpret_cast<uint4*>(&fl);

  if (wv == 0) {
    bf16x8 fb;
    #pragma unroll
    for (int e = 0; e < 8; ++e) fb[e] = (__bf16)0.0f;
    if (hi == 0) {
      float s = 0.0f;
      #pragma unroll
      for (int d = 0; d < kC; d += 4) {
        float4 v = *reinterpret_cast<const float4*>(cb + code * kC + d);
        s = fmaf(v.x, v.x, fmaf(v.y, v.y, fmaf(v.z, v.z, fmaf(v.w, v.w, s))));
      }
      __bf16 h = (__bf16)s;
      fb[0] = h;
      fb[1] = (__bf16)(s - (float)h);
    }
    frags[(c * 9 + 8) * 64 + lane] = *reinterpret_cast<uint4*>(&fb);
  }
  if (t < 32) hist[c * 32 + t] = 0u;
  if (c == 0 && t == 0) lossacc[0] = 0.0f;
}

// ---------------- fused: MFMA argmin + output + loss ------------------------
// Block = 4 waves x 32 sites each (128 sites). All waves share one chunk
// stream staged in LDS (global_load_lds, 2-phase double buffer). Each wave
// scans ALL 1024 codes for its sites -> no cross-wave argmin merge.
__global__ __launch_bounds__(256) void vq_kernel(
    const float* __restrict__ in, const char* __restrict__ fragsB,
    const float* __restrict__ cb, unsigned int* __restrict__ hist,
    float* __restrict__ lossacc, float* __restrict__ qout) {
  __shared__ __align__(16) char sStage[2 * kChunkBytes];
  __shared__ int sIdx[128];
  const int t = threadIdx.x;
  const int lane = t & 63, wv = t >> 6;
  const int lo = lane & 31, hi = lane >> 5;
  const int site = blockIdx.x * 128 + wv * 32 + lo;
  const int b = site >> 12, hw = site & 4095;
  const float* xp = in + b * (kC * kHW) + hw;

  // stage one 9216B chunk into LDS buffer `buf` (all 4 waves cooperate;
  // dest is wave-uniform base + lane*16 per global_load_lds semantics)
  auto stage = [&](int buf, int c) {
    const char* g = fragsB + (size_t)c * kChunkBytes;
    char* l0 = sStage + buf * kChunkBytes;
    __builtin_amdgcn_global_load_lds(
        (const uint32_t*)(g + wv * 1024 + lane * 16),
        (uint32_t*)(l0 + wv * 1024), 16, 0, 0);
    __builtin_amdgcn_global_load_lds(
        (const uint32_t*)(g + 4096 + wv * 1024 + lane * 16),
        (uint32_t*)(l0 + 4096 + wv * 1024), 16, 0, 0);
    if (wv == 0)
      __builtin_amdgcn_global_load_lds(
          (const uint32_t*)(g + 8192 + lane * 16),
          (uint32_t*)(l0 + 8192), 16, 0, 0);
  };

  stage(0, 0);   // prologue: chunk 0 in flight while we build X fragments

  // --- X fragments: bf16 hi/lo split, 8 consecutive d per lane-half ---
  bf16x8 Bh[4], Bl[4];
  #pragma unroll
  for (int ks = 0; ks < 4; ++ks) {
    #pragma unroll
    for (int e = 0; e < 8; ++e) {
      const int d = ks * 16 + hi * 8 + e;
      float v = xp[d * kHW];
      __bf16 h = (__bf16)v;
      Bh[ks][e] = h;
      Bl[ks][e] = (__bf16)(v - (float)h);
    }
  }
  bf16x8 ones;
  #pragma unroll
  for (int e = 0; e < 8; ++e) ones[e] = (__bf16)0.0f;
  if (hi == 0) { ones[0] = (__bf16)1.0f; ones[1] = (__bf16)1.0f; }
  f32x16 zero;
  #pragma unroll
  for (int r = 0; r < 16; ++r) zero[r] = 0.0f;

  float best[16];
  int bch[16];
  #pragma unroll
  for (int r = 0; r < 16; ++r) { best[r] = FLT_MAX; bch[r] = 0; }

  asm volatile("s_waitcnt vmcnt(0)" ::: "memory");
  __syncthreads();

  int buf = 0;
  #pragma unroll 1
  for (int c = 0; c < 32; ++c) {
    if (c + 1 < 32) stage(buf ^ 1, c + 1);     // T14: issue before compute

    const char* lb = sStage + buf * kChunkBytes;
    bf16x8 F8 = *reinterpret_cast<const bf16x8*>(lb + 8 * 1024 + lane * 16);
    bf16x8 F[8];
    #pragma unroll
    for (int j = 0; j < 8; ++j)
      F[j] = *reinterpret_cast<const bf16x8*>(lb + j * 1024 + lane * 16);

    // dist = bias + (-2c).x via 3-pass bf16 split; single chained accumulator
    f32x16 a = __builtin_amdgcn_mfma_f32_32x32x16_bf16(F8, ones, zero, 0, 0, 0);
    #pragma unroll
    for (int ks = 0; ks < 4; ++ks)
      a = __builtin_amdgcn_mfma_f32_32x32x16_bf16(F[ks], Bh[ks], a, 0, 0, 0);
    #pragma unroll
    for (int ks = 0; ks < 4; ++ks)
      a = __builtin_amdgcn_mfma_f32_32x32x16_bf16(F[4 + ks], Bh[ks], a, 0, 0, 0);
    #pragma unroll
    for (int ks = 0; ks < 4; ++ks)
      a = __builtin_amdgcn_mfma_f32_32x32x16_bf16(F[ks], Bl[ks], a, 0, 0, 0);
    #pragma unroll
    for (int r = 0; r < 16; ++r) {
      bool p = a[r] < best[r];         // strict < : earliest chunk wins ties
      best[r] = p ? a[r] : best[r];
      bch[r] = p ? c : bch[r];
    }

    __syncthreads();   // compiler drains vmcnt+lgkmcnt here: stage(c+1) landed,
    buf ^= 1;          // all waves done reading buf -> safe to overwrite next
  }

  // --- per-lane (val, idx) reduce over 16 acc rows, then half-merge ---
  float bv = best[0];
  int bidx = bch[0] * 32 + (hi << 2);       // kloc(r=0) = 0 + 4*hi
  #pragma unroll
  for (int r = 1; r < 16; ++r) {
    const int kloc = (r & 3) + 8 * (r >> 2) + (hi << 2);
    int idx = bch[r] * 32 + kloc;
    float v = best[r];
    if (v < bv || (v == bv && idx < bidx)) { bv = v; bidx = idx; }
  }
  float ov = __shfl_xor(bv, 32, 64);
  int oi = __shfl_xor(bidx, 32, 64);
  if (ov < bv || (ov == bv && oi < bidx)) { bv = ov; bidx = oi; }
  if (hi == 0) {
    sIdx[wv * 32 + lo] = bidx;
    atomicAdd(&hist[bidx], 1u);
  }
  __syncthreads();

  // --- output: quantized = x + (q - x), fused loss ---
  {
    const int s2 = t & 127;                  // site within block
    const int dbase = (t >> 7) << 5;         // d half: 0 or 32
    const int gsite = blockIdx.x * 128 + s2;
    const int b2 = gsite >> 12, hw2 = gsite & 4095;
    const int code = sIdx[s2];
    const float* xr = in + b2 * (kC * kHW) + hw2;
    const float* qr = cb + code * kC + dbase;
    float* op = qout + b2 * (kC * kHW) + hw2;
    float ls = 0.0f;
    #pragma unroll
    for (int j = 0; j < 32; j += 4) {
      float4 qv = *reinterpret_cast<const float4*>(qr + j);
      float q[4] = {qv.x, qv.y, qv.z, qv.w};
      #pragma unroll
      for (int u = 0; u < 4; ++u) {
        const int d = dbase + j + u;
        float xv = xr[d * kHW];
        float diff = q[u] - xv;              // q - x
        ls = fmaf(diff, diff, ls);
        op[d * kHW] = xv + diff;             // straight-through: x + (q-x)
      }
    }
    #pragma unroll
    for (int off = 32; off; off >>= 1) ls += __shfl_xor(ls, off, 64);
    if (lane == 0) atomicAdd(lossacc, ls);
  }
}

// ---------------- finalize: loss scalar + perplexity ------------------------
__global__ __launch_bounds__(1024) void finalize_kernel(
    const unsigned int* __restrict__ hist, const float* __restrict__ lossacc,
    const float* __restrict__ beta, float* __restrict__ out) {
  __shared__ float red[16];
  const int t = threadIdx.x;
  float e = (float)hist[t] * kInvN;
  float term = e * logf(e + 1e-10f);
  #pragma unroll
  for (int off = 32; off; off >>= 1) term += __shfl_xor(term, off, 64);
  if ((t & 63) == 0) red[t >> 6] = term;
  __syncthreads();
  if (t == 0) {
    float h = 0.0f;
    #pragma unroll
    for (int i = 0; i < 16; ++i) h += red[i];
    out[1 + 4194304] = expf(-h);                                  // perplexity
    out[0] = lossacc[0] * (1.0f + beta[0]) * 10.0f / 4194304.0f;  // loss
  }
}
}  // namespace

extern "C" void kernel_launch(void* const* d_in, const int* in_sizes, int n_in,
                              void* d_out, int out_size, void* d_ws, size_t ws_size,
                              hipStream_t stream) {
  const float* inputs = (const float*)d_in[0];   // [16,64,64,64] fp32
  const float* cb = (const float*)d_in[1];       // [1024,64] fp32
  const float* beta = (const float*)d_in[2];     // scalar
  float* out = (float*)d_out;                    // [1 + 4194304 + 1]

  uint4* frags = (uint4*)d_ws;                                        // 294912 B
  unsigned int* hist = (unsigned int*)((char*)d_ws + 294912);         // 4 KB
  float* lossacc = (float*)((char*)d_ws + 294912 + 4096);             // 4 B

  prep_kernel<<<32, 256, 0, stream>>>(cb, frags, hist, lossacc);
  vq_kernel<<<512, 256, 0, stream>>>(inputs, (const char*)d_ws, cb, hist,
                                     lossacc, out + 1);
  finalize_kernel<<<1, 1024, 0, stream>>>(hist, lossacc, beta, out);
}

// Round 8
// 121.234 us; speedup vs baseline: 2.1333x; 1.1412x over previous
//
#include <hip/hip_runtime.h>
#include <cfloat>

typedef __bf16 bf16x8 __attribute__((ext_vector_type(8)));
typedef float f32x16 __attribute__((ext_vector_type(16)));

namespace {
constexpr int kHW = 4096;     // 64*64 spatial per image
constexpr int kC = 64;        // channels == code dim
constexpr float kInvN = 1.0f / 65536.0f;

// ws layout (bytes): [0, 294912): A-frags (32 chunks * 9 slots * 64 lanes * 16B)
//   [294912, +4096): hist   [299008, +16): lossacc   [299024, +262144): idx
// Frag slot order per chunk: 0..3 = Ah(ks), 4..7 = Al(ks), 8 = bias.

// ---------------- prep: build -2*C bf16-split fragments + bias frag ---------
__global__ __launch_bounds__(256) void prep_kernel(
    const float* __restrict__ cb, uint4* __restrict__ frags,
    unsigned int* __restrict__ hist, float* __restrict__ lossacc) {
  const int c = blockIdx.x;        // chunk of 32 codes
  const int t = threadIdx.x;
  const int lane = t & 63, wv = t >> 6;
  const int lo = lane & 31, hi = lane >> 5;
  const int code = c * 32 + lo;
  const int ks = wv;

  const float* row = cb + code * kC + ks * 16 + hi * 8;
  float4 v0 = *reinterpret_cast<const float4*>(row);
  float4 v1 = *reinterpret_cast<const float4*>(row + 4);
  float vv[8] = {v0.x, v0.y, v0.z, v0.w, v1.x, v1.y, v1.z, v1.w};
  bf16x8 fh, fl;
  #pragma unroll
  for (int e = 0; e < 8; ++e) {
    float v = -2.0f * vv[e];
    __bf16 h = (__bf16)v;
    fh[e] = h;
    fl[e] = (__bf16)(v - (float)h);
  }
  frags[(c * 9 + ks) * 64 + lane] = *reinterpret_cast<uint4*>(&fh);
  frags[(c * 9 + 4 + ks) * 64 + lane] = *reinterpret_cast<uint4*>(&fl);

  if (wv == 0) {
    bf16x8 fb;
    #pragma unroll
    for (int e = 0; e < 8; ++e) fb[e] = (__bf16)0.0f;
    if (hi == 0) {
      float s = 0.0f;
      #pragma unroll
      for (int d = 0; d < kC; d += 4) {
        float4 v = *reinterpret_cast<const float4*>(cb + code * kC + d);
        s = fmaf(v.x, v.x, fmaf(v.y, v.y, fmaf(v.z, v.z, fmaf(v.w, v.w, s))));
      }
      __bf16 h = (__bf16)s;
      fb[0] = h;
      fb[1] = (__bf16)(s - (float)h);
    }
    frags[(c * 9 + 8) * 64 + lane] = *reinterpret_cast<uint4*>(&fb);
  }
  if (t < 32) hist[c * 32 + t] = 0u;
  if (c == 0 && t == 0) lossacc[0] = 0.0f;
}

// ---------------- argmin GEMM only (R5 core, fission ablation) --------------
// Block = 4 waves owning 64 sites. Wave wv: site-group (wv&1), K-half (wv>>1)
// of 16 chunks. Cross-half merge via LDS; writes per-site idx to ws.
__global__ __launch_bounds__(256) void vq_argmin_kernel(
    const float* __restrict__ in, const bf16x8* __restrict__ frags,
    unsigned int* __restrict__ hist, unsigned int* __restrict__ idxOut) {
  __shared__ float sVal[4][32];
  __shared__ int sIdxW[4][32];
  const int t = threadIdx.x;
  const int lane = t & 63, wv = t >> 6;
  const int lo = lane & 31, hi = lane >> 5;
  const int sg2 = wv & 1, kh = wv >> 1;
  const int site = blockIdx.x * 64 + sg2 * 32 + lo;
  const int b = site >> 12, hw = site & 4095;
  const float* xp = in + b * (kC * kHW) + hw;

  // --- X fragments: bf16 hi/lo split, 8 consecutive d per lane-half ---
  bf16x8 Bh[4], Bl[4];
  #pragma unroll
  for (int ks = 0; ks < 4; ++ks) {
    #pragma unroll
    for (int e = 0; e < 8; ++e) {
      const int d = ks * 16 + hi * 8 + e;
      float v = xp[d * kHW];
      __bf16 h = (__bf16)v;
      Bh[ks][e] = h;
      Bl[ks][e] = (__bf16)(v - (float)h);
    }
  }
  bf16x8 ones;
  #pragma unroll
  for (int e = 0; e < 8; ++e) ones[e] = (__bf16)0.0f;
  if (hi == 0) { ones[0] = (__bf16)1.0f; ones[1] = (__bf16)1.0f; }
  f32x16 zero;
  #pragma unroll
  for (int r = 0; r < 16; ++r) zero[r] = 0.0f;

  float best[16];
  int bch[16];
  #pragma unroll
  for (int r = 0; r < 16; ++r) { best[r] = FLT_MAX; bch[r] = 0; }

  const bf16x8* fA = frags + lane;   // entry j of chunk c at fA[(c*9+j)*64]

  bf16x8 A0[9], A1[9];
  auto prefetch = [&](bf16x8(&F)[9], int c) {
    #pragma unroll
    for (int j = 0; j < 9; ++j) F[j] = fA[(c * 9 + j) * 64];
  };
  auto compute = [&](const bf16x8(&F)[9], int c) {
    // dist = bias + (-2c).x via 3-pass bf16 split; single chained accumulator
    f32x16 a = __builtin_amdgcn_mfma_f32_32x32x16_bf16(F[8], ones, zero, 0, 0, 0);
    #pragma unroll
    for (int ks = 0; ks < 4; ++ks)
      a = __builtin_amdgcn_mfma_f32_32x32x16_bf16(F[ks], Bh[ks], a, 0, 0, 0);
    #pragma unroll
    for (int ks = 0; ks < 4; ++ks)
      a = __builtin_amdgcn_mfma_f32_32x32x16_bf16(F[4 + ks], Bh[ks], a, 0, 0, 0);
    #pragma unroll
    for (int ks = 0; ks < 4; ++ks)
      a = __builtin_amdgcn_mfma_f32_32x32x16_bf16(F[ks], Bl[ks], a, 0, 0, 0);
    #pragma unroll
    for (int r = 0; r < 16; ++r) {
      bool p = a[r] < best[r];         // strict < : earliest chunk wins ties
      best[r] = p ? a[r] : best[r];
      bch[r] = p ? c : bch[r];
    }
  };

  const int c0 = kh * 16;
  prefetch(A0, c0);
  #pragma unroll 1
  for (int c = c0; c < c0 + 16; c += 2) {
    prefetch(A1, c + 1);
    compute(A0, c);
    if (c + 2 < c0 + 16) prefetch(A0, c + 2);
    compute(A1, c + 1);
  }

  // --- per-lane (val, idx) reduce over 16 acc rows, then half-merge ---
  float bv = best[0];
  int bidx = bch[0] * 32 + (hi << 2);       // kloc(r=0) = 0 + 4*hi
  #pragma unroll
  for (int r = 1; r < 16; ++r) {
    const int kloc = (r & 3) + 8 * (r >> 2) + (hi << 2);
    int idx = bch[r] * 32 + kloc;
    float v = best[r];
    if (v < bv || (v == bv && idx < bidx)) { bv = v; bidx = idx; }
  }
  float ov = __shfl_xor(bv, 32, 64);
  int oi = __shfl_xor(bidx, 32, 64);
  if (ov < bv || (ov == bv && oi < bidx)) { bv = ov; bidx = oi; }
  if (hi == 0) {
    sVal[wv][lo] = bv;
    sIdxW[wv][lo] = bidx;
  }
  __syncthreads();
  // waves 0,1 (K-half 0) merge with partner wave (wv+2, K-half 1)
  if (wv < 2 && hi == 0) {
    float v2 = sVal[wv + 2][lo];
    int i2 = sIdxW[wv + 2][lo];
    if (v2 < bv || (v2 == bv && i2 < bidx)) { bv = v2; bidx = i2; }
    idxOut[site] = (unsigned int)bidx;
    atomicAdd(&hist[bidx], 1u);
  }
}

// ---------------- epilogue: gather + ST output + loss -----------------------
// 256 blocks x 256 thr. Block owns 256 sites (one image strip). Thread:
// 4 consecutive sites (float4 x-loads) x 16 dims. Loss: block-reduced,
// ONE atomic per block (was one per wave).
__global__ __launch_bounds__(256) void epilogue_kernel(
    const float* __restrict__ in, const float* __restrict__ cb,
    const unsigned int* __restrict__ idx, float* __restrict__ lossacc,
    float* __restrict__ qout) {
  __shared__ float sRed[4];
  const int t = threadIdx.x;
  const int sg = t & 63, dg = t >> 6;
  const int siteBase = blockIdx.x * 256 + sg * 4;
  const int b = siteBase >> 12, hw = siteBase & 4095;
  const float* xb = in + b * (kC * kHW) + hw;
  float* ob = qout + b * (kC * kHW) + hw;
  uint4 cc = *reinterpret_cast<const uint4*>(idx + siteBase);
  const float* q0 = cb + cc.x * kC;
  const float* q1 = cb + cc.y * kC;
  const float* q2 = cb + cc.z * kC;
  const float* q3 = cb + cc.w * kC;
  float ls = 0.0f;
  #pragma unroll
  for (int j = 0; j < 16; ++j) {
    const int d = dg * 16 + j;
    float4 xv = *reinterpret_cast<const float4*>(xb + d * kHW);
    float d0 = q0[d] - xv.x;   // q - x
    float d1 = q1[d] - xv.y;
    float d2 = q2[d] - xv.z;
    float d3 = q3[d] - xv.w;
    ls = fmaf(d0, d0, ls);
    ls = fmaf(d1, d1, ls);
    ls = fmaf(d2, d2, ls);
    ls = fmaf(d3, d3, ls);
    float* o = ob + d * kHW;               // qout is d_out+1: 4B-misaligned for
    o[0] = xv.x + d0;                      // float4 -> scalar stores (coalesced
    o[1] = xv.y + d1;                      // 256B per wave-instr anyway)
    o[2] = xv.z + d2;
    o[3] = xv.w + d3;
  }
  #pragma unroll
  for (int off = 32; off; off >>= 1) ls += __shfl_xor(ls, off, 64);
  if ((t & 63) == 0) sRed[t >> 6] = ls;
  __syncthreads();
  if (t == 0) {
    float s = (sRed[0] + sRed[1]) + (sRed[2] + sRed[3]);
    atomicAdd(lossacc, s);
  }
}

// ---------------- finalize: loss scalar + perplexity ------------------------
__global__ __launch_bounds__(1024) void finalize_kernel(
    const unsigned int* __restrict__ hist, const float* __restrict__ lossacc,
    const float* __restrict__ beta, float* __restrict__ out) {
  __shared__ float red[16];
  const int t = threadIdx.x;
  float e = (float)hist[t] * kInvN;
  float term = e * logf(e + 1e-10f);
  #pragma unroll
  for (int off = 32; off; off >>= 1) term += __shfl_xor(term, off, 64);
  if ((t & 63) == 0) red[t >> 6] = term;
  __syncthreads();
  if (t == 0) {
    float h = 0.0f;
    #pragma unroll
    for (int i = 0; i < 16; ++i) h += red[i];
    out[1 + 4194304] = expf(-h);                                  // perplexity
    out[0] = lossacc[0] * (1.0f + beta[0]) * 10.0f / 4194304.0f;  // loss
  }
}
}  // namespace

extern "C" void kernel_launch(void* const* d_in, const int* in_sizes, int n_in,
                              void* d_out, int out_size, void* d_ws, size_t ws_size,
                              hipStream_t stream) {
  const float* inputs = (const float*)d_in[0];   // [16,64,64,64] fp32
  const float* cb = (const float*)d_in[1];       // [1024,64] fp32
  const float* beta = (const float*)d_in[2];     // scalar
  float* out = (float*)d_out;                    // [1 + 4194304 + 1]

  uint4* frags = (uint4*)d_ws;                                        // 294912 B
  unsigned int* hist = (unsigned int*)((char*)d_ws + 294912);         // 4 KB
  float* lossacc = (float*)((char*)d_ws + 299008);                    // 16 B
  unsigned int* idx = (unsigned int*)((char*)d_ws + 299024);          // 256 KB

  prep_kernel<<<32, 256, 0, stream>>>(cb, frags, hist, lossacc);
  vq_argmin_kernel<<<1024, 256, 0, stream>>>(inputs, (const bf16x8*)frags,
                                             hist, idx);
  epilogue_kernel<<<256, 256, 0, stream>>>(inputs, cb, idx, lossacc, out + 1);
  finalize_kernel<<<1, 1024, 0, stream>>>(hist, lossacc, beta, out);
}